// Round 11
// baseline (111.945 us; speedup 1.0000x reference)
//
#include <hip/hip_runtime.h>
#include <hip/hip_bf16.h>
#include <cstdint>

typedef __attribute__((ext_vector_type(8))) short short8;
typedef __attribute__((ext_vector_type(4))) short short4v;
typedef __attribute__((ext_vector_type(4))) float f32x4;

static constexpr int HWPIX = 16384;   // 128*128
static constexpr int NCH   = 512;
static constexpr int GCHK  = 32;      // gram pixel chunks (512 px each)

__device__ __forceinline__ unsigned short f2bf(float f) {
    unsigned int u = __float_as_uint(f);
    u = (u + 0x7fffu + ((u >> 16) & 1u)) >> 16;
    return (unsigned short)u;
}

// Conv: 64co x 64px (half image row) per block; kh in sections of 8 input rows.
// K-dim per section: kw outer, icr = ic*8 + rr inner; SROW = 24.
// B elem offset = col*24 + seg*8 -> linear in chunk t, no division in loop.
// K-SPLIT: wave w handles chunks t = w, w+4, ...; wave computes 64co x 64px
// (acc = 64 regs -> 3 waves/SIMD at <=170 VGPR). f32 partials reduced via LDS.
template<int K> struct KG {
    static constexpr int P     = (K - 1) / 2;
    static constexpr int NSEC  = (K + 7) / 8;          // kh sections
    static constexpr int SEGS  = 3 * K;                // octet-segments per section
    static constexpr int NCHK  = (SEGS + 3) / 4;       // MFMA K-32 chunks per section
    static constexpr int NCHKP = ((NCHK + 3) / 4) * 4; // padded to 4 waves
    static constexpr int COLS  = 64 + K - 1;           // half-row tile + halo
    static constexpr int XPAD  = 128;
    static constexpr int XSE   = COLS * 24 + XPAD;
};
// max elem read: col 63 -> 1512, + (NCHKP*4-1)*8 + 8 = 1512 + NCHKP*32
static_assert(1512 + KG< 3>::NCHKP * 32 <= KG< 3>::XSE, "pad3");
static_assert(1512 + KG< 5>::NCHKP * 32 <= KG< 5>::XSE, "pad5");
static_assert(1512 + KG< 7>::NCHKP * 32 <= KG< 7>::XSE, "pad7");
static_assert(1512 + KG<11>::NCHKP * 32 <= KG<11>::XSE, "pad11");
static_assert(1512 + KG<15>::NCHKP * 32 <= KG<15>::XSE, "pad15");
static_assert(1512 + KG<23>::NCHKP * 32 <= KG<23>::XSE, "pad23");
static_assert(1512 + KG<37>::NCHKP * 32 <= KG<37>::XSE, "pad37");
static_assert(1512 + KG<55>::NCHKP * 32 <= KG<55>::XSE, "pad55");
static_assert(KG<55>::XSE * 2 <= 18432, "xs fits smem");

struct PtrArgs {
    const float* w[8];
    const float* bias[8];
    unsigned short* wpk[8];
    int cum[9];            // cumulative NSEC*NCHKP per filter
};

// ---------------- weight repack (A layout unchanged from r10) ----------------
template<int K>
__device__ void repack_body(const float* __restrict__ w, unsigned short* __restrict__ wpk, int t) {
    constexpr int NCHKP = KG<K>::NCHKP;
    const int sec = t / NCHKP;
    const int tc  = t - sec * NCHKP;
    const int tid = threadIdx.x;
    const int co  = ((tid >> 6) << 4) + (tid & 15);
    const int seg = tc * 4 + ((tid >> 4) & 3);
    int kw = 0, r = 0;
    const bool vseg = seg < KG<K>::SEGS;
    if (vseg) { kw = seg / 3; r = seg - kw * 3; }
    short8 o;
    #pragma unroll
    for (int j = 0; j < 8; ++j) {
        const int icr = r * 8 + j;
        const int ic  = icr >> 3;
        const int kh  = sec * 8 + (icr & 7);
        float v = 0.f;
        if (vseg && kh < K)
            v = w[((co * 3 + ic) * K + kh) * K + kw];
        o[j] = (short)f2bf(v);
    }
    *reinterpret_cast<short8*>(wpk + ((size_t)(t * 256 + tid)) * 8) = o;
}

__global__ __launch_bounds__(256) void repack_all(PtrArgs a) {
    const int blk = blockIdx.x;
    int f = 0;
    #pragma unroll
    for (int i = 0; i < 8; ++i) if (blk >= a.cum[i + 1]) f = i + 1;
    const int t = blk - a.cum[f];
    switch (f) {
        case 0: repack_body< 3>(a.w[0], a.wpk[0], t); break;
        case 1: repack_body< 5>(a.w[1], a.wpk[1], t); break;
        case 2: repack_body< 7>(a.w[2], a.wpk[2], t); break;
        case 3: repack_body<11>(a.w[3], a.wpk[3], t); break;
        case 4: repack_body<15>(a.w[4], a.wpk[4], t); break;
        case 5: repack_body<23>(a.w[5], a.wpk[5], t); break;
        case 6: repack_body<37>(a.w[6], a.wpk[6], t); break;
        case 7: repack_body<55>(a.w[7], a.wpk[7], t); break;
    }
}

// ---- conv: 256 thr, 4 waves; wave = 64co x 64px x (1/4 of K-chunks) ----
#define MFMA_BF16 __builtin_amdgcn_mfma_f32_16x16x32_bf16

template<int K>
__device__ void conv_body(const float* __restrict__ x, const unsigned short* __restrict__ wpk,
                          const float* __restrict__ bias, unsigned short* __restrict__ feat,
                          int cbase, char* smem, int bx)
{
    constexpr int P     = KG<K>::P;
    constexpr int NCHKP = KG<K>::NCHKP;
    constexpr int NSEC  = KG<K>::NSEC;
    constexpr int COLS  = KG<K>::COLS;

    unsigned short* xs = (unsigned short*)smem;
    float* red = (float*)smem;          // aliases xs; used only after xs is dead

    const int tid = threadIdx.x;
    const int ph  = bx & 1;             // px half: 0 -> cols 0..63, 1 -> 64..127
    const int h   = (bx >> 1) & 127;    // image row
    const int b   = bx >> 8;            // batch

    const int lane = tid & 63;
    const int wv   = tid >> 6;          // 0..3 -> K-chunk quarter
    const int ln15 = lane & 15;
    const int lg   = lane >> 4;         // k-octet 0..3

    // zero the pad region (tail-seg reads land here; stays zero while xs lives)
    for (int i = tid * 4; i < KG<K>::XPAD; i += 1024)
        *reinterpret_cast<short4v*>(xs + COLS * 24 + i) = short4v{0, 0, 0, 0};

    f32x4 acc[4][4] = {};               // [costrip][pxstrip]
    const float* xb = x + (size_t)b * 3 * HWPIX;
    const int col0 = ph * 64 - P;       // global col of xs col 0

    for (int sec = 0; sec < NSEC; ++sec) {
        if (sec > 0) __syncthreads();   // all waves done reading previous section
        for (int e = tid * 4; e < 24 * COLS; e += 1024) {
            const int c  = e / 24;
            const int i0 = e - c * 24;
            const int col = col0 + c;
            short4v pk;
            #pragma unroll
            for (int j = 0; j < 4; ++j) {
                const int icr = i0 + j;
                const int ic  = icr >> 3;
                const int row = h + sec * 8 + (icr & 7) - P;
                float v = 0.f;
                if ((unsigned)row < 128u && (unsigned)col < 128u)
                    v = xb[ic * HWPIX + row * 128 + col];
                pk[j] = (short)f2bf(v);
            }
            *reinterpret_cast<short4v*>(xs + e) = pk;
        }
        __syncthreads();

        const unsigned short* ws = wpk + (size_t)sec * NCHKP * 2048 + lane * 8;
        for (int tt = 0; tt < NCHKP / 4; ++tt) {
            const int t = tt * 4 + wv;
            const unsigned short* ap = ws + (size_t)t * 2048;
            short8 a0 = *reinterpret_cast<const short8*>(ap);
            short8 a1 = *reinterpret_cast<const short8*>(ap + 512);
            short8 a2 = *reinterpret_cast<const short8*>(ap + 1024);
            short8 a3 = *reinterpret_cast<const short8*>(ap + 1536);
            const unsigned short* bp = xs + ln15 * 24 + lg * 8 + t * 32;
            short8 b0 = *reinterpret_cast<const short8*>(bp);
            short8 b1 = *reinterpret_cast<const short8*>(bp + 1 * 384);
            short8 b2 = *reinterpret_cast<const short8*>(bp + 2 * 384);
            short8 b3 = *reinterpret_cast<const short8*>(bp + 3 * 384);

            acc[0][0] = MFMA_BF16(a0, b0, acc[0][0], 0, 0, 0);
            acc[0][1] = MFMA_BF16(a0, b1, acc[0][1], 0, 0, 0);
            acc[0][2] = MFMA_BF16(a0, b2, acc[0][2], 0, 0, 0);
            acc[0][3] = MFMA_BF16(a0, b3, acc[0][3], 0, 0, 0);
            acc[1][0] = MFMA_BF16(a1, b0, acc[1][0], 0, 0, 0);
            acc[1][1] = MFMA_BF16(a1, b1, acc[1][1], 0, 0, 0);
            acc[1][2] = MFMA_BF16(a1, b2, acc[1][2], 0, 0, 0);
            acc[1][3] = MFMA_BF16(a1, b3, acc[1][3], 0, 0, 0);
            acc[2][0] = MFMA_BF16(a2, b0, acc[2][0], 0, 0, 0);
            acc[2][1] = MFMA_BF16(a2, b1, acc[2][1], 0, 0, 0);
            acc[2][2] = MFMA_BF16(a2, b2, acc[2][2], 0, 0, 0);
            acc[2][3] = MFMA_BF16(a2, b3, acc[2][3], 0, 0, 0);
            acc[3][0] = MFMA_BF16(a3, b0, acc[3][0], 0, 0, 0);
            acc[3][1] = MFMA_BF16(a3, b1, acc[3][1], 0, 0, 0);
            acc[3][2] = MFMA_BF16(a3, b2, acc[3][2], 0, 0, 0);
            acc[3][3] = MFMA_BF16(a3, b3, acc[3][3], 0, 0, 0);
        }
    }

    // ---- cross-wave reduction via LDS (xs dead after this barrier) ----
    __syncthreads();
    const float bv  = bias[tid >> 2];
    const int   eco = tid >> 2;          // 0..63
    const int   ep0 = (tid & 3) * 4;     // 0,4,8,12
    const size_t fbase = (((size_t)(b * NCH + cbase + eco)) << 14) + h * 128 + ph * 64;

    #pragma unroll
    for (int q = 0; q < 4; ++q) {
        if (q > 0) __syncthreads();      // previous pass's reads done
        #pragma unroll
        for (int cs = 0; cs < 4; ++cs)
            #pragma unroll
            for (int i = 0; i < 4; ++i)
                red[(wv * 64 + cs * 16 + lg * 4 + i) * 18 + ln15] = acc[cs][q][i];
        __syncthreads();
        short4v o;
        #pragma unroll
        for (int j = 0; j < 4; ++j) {
            const int px = ep0 + j;
            float v = red[(0 * 64 + eco) * 18 + px] + red[(1 * 64 + eco) * 18 + px]
                    + red[(2 * 64 + eco) * 18 + px] + red[(3 * 64 + eco) * 18 + px];
            o[j] = (short)f2bf(fmaxf(v + bv, 0.f));
        }
        *reinterpret_cast<short4v*>(feat + fbase + q * 16 + ep0) = o;
    }
}

__global__ __launch_bounds__(256, 3) void conv_all(const float* __restrict__ x,
                                                   PtrArgs a, unsigned short* __restrict__ feat)
{
    __shared__ __align__(16) char smem[18432];   // max(xs 5920B, red 4*64*18*4B)
    // LPT dispatch: heaviest filter (K=55) first so it spreads over all CUs
    switch (7 - blockIdx.y) {
        case 0: conv_body< 3>(x, a.wpk[0], a.bias[0], feat, 0 * 64, smem, blockIdx.x); break;
        case 1: conv_body< 5>(x, a.wpk[1], a.bias[1], feat, 1 * 64, smem, blockIdx.x); break;
        case 2: conv_body< 7>(x, a.wpk[2], a.bias[2], feat, 2 * 64, smem, blockIdx.x); break;
        case 3: conv_body<11>(x, a.wpk[3], a.bias[3], feat, 3 * 64, smem, blockIdx.x); break;
        case 4: conv_body<15>(x, a.wpk[4], a.bias[4], feat, 4 * 64, smem, blockIdx.x); break;
        case 5: conv_body<23>(x, a.wpk[5], a.bias[5], feat, 5 * 64, smem, blockIdx.x); break;
        case 6: conv_body<37>(x, a.wpk[6], a.bias[6], feat, 6 * 64, smem, blockIdx.x); break;
        case 7: conv_body<55>(x, a.wpk[7], a.bias[7], feat, 7 * 64, smem, blockIdx.x); break;
    }
}

// ---------------- gram via MFMA (unchanged, passing since r4) ----------------
__global__ __launch_bounds__(256) void gram_mfma(
    const unsigned short* __restrict__ feat, const int* __restrict__ perm,
    float* __restrict__ part)
{
    __shared__ __align__(16) unsigned short tile[64 * 256];
    __shared__ int permch[64];

    const int bg = blockIdx.y, chunk = blockIdx.x;
    const int b = bg >> 3, gq = bg & 7;
    const int tid = threadIdx.x;

    if (tid < 64) permch[tid] = perm[gq * 64 + tid];
    __syncthreads();

    const int lane = tid & 63;
    const int wv   = tid >> 6;
    const int ln15 = lane & 15;
    const int kg   = lane >> 4;

    f32x4 acc[4] = {};
    const size_t pxbase = (size_t)chunk * 512;

    for (int p2 = 0; p2 < 2; ++p2) {
        {
            const int r0 = tid >> 5;        // 0..7
            const int g  = tid & 31;        // 16B group 0..31
            #pragma unroll
            for (int it = 0; it < 8; ++it) {
                const int r = it * 8 + r0;
                const unsigned short* src =
                    feat + (((size_t)(b * NCH + permch[r])) << 14) + pxbase + p2 * 256 + g * 8;
                short8 v = *reinterpret_cast<const short8*>(src);
                *reinterpret_cast<short8*>(tile + r * 256 + ((g ^ (r & 7)) * 8)) = v;
            }
        }
        __syncthreads();
        #pragma unroll
        for (int t = 0; t < 8; ++t) {
            const int g  = t * 4 + kg;
            const int ra = wv * 16 + ln15;
            short8 av = *reinterpret_cast<const short8*>(tile + ra * 256 + ((g ^ (ra & 7)) * 8));
            #pragma unroll
            for (int cs = 0; cs < 4; ++cs) {
                const int rb = cs * 16 + ln15;
                short8 bv = *reinterpret_cast<const short8*>(tile + rb * 256 + ((g ^ (rb & 7)) * 8));
                acc[cs] = MFMA_BF16(av, bv, acc[cs], 0, 0, 0);
            }
        }
        __syncthreads();
    }

    float* pp = part + ((size_t)bg * GCHK + chunk) * 4096;
    #pragma unroll
    for (int cs = 0; cs < 4; ++cs)
        #pragma unroll
        for (int i = 0; i < 4; ++i) {
            const int row = wv * 16 + kg * 4 + i;
            const int col = cs * 16 + ln15;
            pp[row * 64 + col] = acc[cs][i];
        }
}

__global__ __launch_bounds__(256) void gram_reduce(
    const float* __restrict__ part, float* __restrict__ out)
{
    const int idx = blockIdx.x * 256 + threadIdx.x;   // 0..65535
    const int bg  = idx >> 12;
    const int e   = idx & 4095;
    const float* p = part + (size_t)bg * GCHK * 4096 + e;
    float s = 0.f;
    #pragma unroll
    for (int c = 0; c < GCHK; ++c) s += p[c * 4096];
    out[idx] = s;
}

extern "C" void kernel_launch(void* const* d_in, const int* in_sizes, int n_in,
                              void* d_out, int out_size, void* d_ws, size_t ws_size,
                              hipStream_t stream) {
    const float* x = (const float*)d_in[0];
    const int* perm = (const int*)d_in[17];

    // ws: feat bf16 32MiB | part 8MiB | wpk 572 chunks * 4KiB = 2.29MiB
    unsigned short* feat = (unsigned short*)d_ws;
    float* part = (float*)((char*)d_ws + (size_t)2 * NCH * HWPIX * sizeof(unsigned short));
    unsigned short* wpk0 = (unsigned short*)((char*)part + (size_t)16 * GCHK * 4096 * sizeof(float));
    float* out = (float*)d_out;

    const int nchk[8] = { KG<3>::NSEC * KG<3>::NCHKP,  KG<5>::NSEC * KG<5>::NCHKP,
                          KG<7>::NSEC * KG<7>::NCHKP,  KG<11>::NSEC * KG<11>::NCHKP,
                          KG<15>::NSEC * KG<15>::NCHKP, KG<23>::NSEC * KG<23>::NCHKP,
                          KG<37>::NSEC * KG<37>::NCHKP, KG<55>::NSEC * KG<55>::NCHKP };
    PtrArgs a;
    int acc = 0;
    for (int i = 0; i < 8; ++i) {
        a.w[i]    = (const float*)d_in[1 + 2 * i];
        a.bias[i] = (const float*)d_in[2 + 2 * i];
        a.wpk[i]  = wpk0 + (size_t)acc * 2048;
        a.cum[i]  = acc;
        acc += nchk[i];
    }
    a.cum[8] = acc;   // 572 total chunk-sections

    repack_all<<<acc, 256, 0, stream>>>(a);
    conv_all<<<dim3(512, 8), 256, 0, stream>>>(x, a, feat);
    gram_mfma<<<dim3(GCHK, 16), 256, 0, stream>>>(feat, perm, part);
    gram_reduce<<<dim3(65536 / 256), 256, 0, stream>>>(part, out);
}

// Round 12
// 105.848 us; speedup vs baseline: 1.0576x; 1.0576x over previous
//
#include <hip/hip_runtime.h>
#include <hip/hip_bf16.h>
#include <cstdint>

typedef __attribute__((ext_vector_type(8))) short short8;
typedef __attribute__((ext_vector_type(4))) short short4v;
typedef __attribute__((ext_vector_type(4))) float f32x4;
typedef __attribute__((ext_vector_type(16))) float f32x16;

static constexpr int HWPIX = 16384;   // 128*128
static constexpr int NCH   = 512;
static constexpr int GCHK  = 32;      // gram pixel chunks (512 px each)

__device__ __forceinline__ unsigned short f2bf(float f) {
    unsigned int u = __float_as_uint(f);
    u = (u + 0x7fffu + ((u >> 16) & 1u)) >> 16;
    return (unsigned short)u;
}

// Conv: 64co x 128px (one image row) per block; kh in sections of 8 input rows.
// K-dim per section: kw outer, icr = ic*8 + rr inner; col stride 24 elems.
// B elem offset = col*24 + seg*8 (kw*24 + r*8 = seg*8) -> linear in chunk.
// MFMA 32x32x16: per K16-chunk per wave: 2 A b128 (global) + 4 B b128 (LDS)
// + 8 MFMA. K-split: wave wv owns chunks t16 = wv, wv+4, ... (NCHKP16 % 4 == 0).
// xs DOUBLE-BUFFERED: stage sec s+1 while computing sec s; 1 barrier/section.
template<int K> struct KG {
    static constexpr int P       = (K - 1) / 2;
    static constexpr int NSEC    = (K + 7) / 8;            // kh sections
    static constexpr int SEGS    = 3 * K;                  // octet-segments/section
    static constexpr int NCHK16  = (SEGS + 1) / 2;         // K16 chunks/section
    static constexpr int NCHKP16 = ((NCHK16 + 3) / 4) * 4; // padded to 4 waves
    static constexpr int COLS    = 128 + K - 1;
    static constexpr int XPAD    = 128;
    static constexpr int XSE     = COLS * 24 + XPAD;       // one buffer, elems
};
// max B elem touched: (96+31)*24 + NCHKP16*16 - 1  (tail segs read pad, zero wgts)
static_assert(3048 + KG< 3>::NCHKP16 * 16 <= KG< 3>::XSE, "pad3");
static_assert(3048 + KG< 5>::NCHKP16 * 16 <= KG< 5>::XSE, "pad5");
static_assert(3048 + KG< 7>::NCHKP16 * 16 <= KG< 7>::XSE, "pad7");
static_assert(3048 + KG<11>::NCHKP16 * 16 <= KG<11>::XSE, "pad11");
static_assert(3048 + KG<15>::NCHKP16 * 16 <= KG<15>::XSE, "pad15");
static_assert(3048 + KG<23>::NCHKP16 * 16 <= KG<23>::XSE, "pad23");
static_assert(3048 + KG<37>::NCHKP16 * 16 <= KG<37>::XSE, "pad37");
static_assert(3048 + KG<55>::NCHKP16 * 16 <= KG<55>::XSE, "pad55");
static_assert(2 * KG<55>::XSE * 2 <= 33792, "dbuf fits smem");   // 17984 B

struct PtrArgs {
    const float* w[8];
    const float* bias[8];
    unsigned short* wpk[8];
    int cum[9];            // cumulative NSEC*NCHKP16 per filter
};

// ---------------- weight repack for 32x32x16 A fragments ----------------
// per filter: [sec][t16][strip 0..1][lane 0..63][8]; lane holds co=strip*32+(lane&31),
// seg = 2*t16 + (lane>>5), elems j: icr=r*8+j -> ic=icr>>3, kh=sec*8+(icr&7), kw.
template<int K>
__device__ void repack_body(const float* __restrict__ w, unsigned short* __restrict__ wpk, int t) {
    constexpr int NCHKP16 = KG<K>::NCHKP16;
    const int sec = t / NCHKP16;
    const int t16 = t - sec * NCHKP16;
    const int tid = threadIdx.x;
    if (tid >= 128) return;
    const int strip = tid >> 6;
    const int lane  = tid & 63;
    const int co    = strip * 32 + (lane & 31);
    const int seg   = 2 * t16 + (lane >> 5);
    int kw = 0, r = 0;
    const bool vseg = seg < KG<K>::SEGS;
    if (vseg) { kw = seg / 3; r = seg - kw * 3; }
    short8 o;
    #pragma unroll
    for (int j = 0; j < 8; ++j) {
        const int icr = r * 8 + j;
        const int ic  = icr >> 3;
        const int kh  = sec * 8 + (icr & 7);
        float v = 0.f;
        if (vseg && kh < K)
            v = w[((co * 3 + ic) * K + kh) * K + kw];
        o[j] = (short)f2bf(v);
    }
    *reinterpret_cast<short8*>(wpk + ((size_t)t * 128 + strip * 64 + lane) * 8) = o;
}

__global__ __launch_bounds__(256) void repack_all(PtrArgs a) {
    const int blk = blockIdx.x;
    int f = 0;
    #pragma unroll
    for (int i = 0; i < 8; ++i) if (blk >= a.cum[i + 1]) f = i + 1;
    const int t = blk - a.cum[f];
    switch (f) {
        case 0: repack_body< 3>(a.w[0], a.wpk[0], t); break;
        case 1: repack_body< 5>(a.w[1], a.wpk[1], t); break;
        case 2: repack_body< 7>(a.w[2], a.wpk[2], t); break;
        case 3: repack_body<11>(a.w[3], a.wpk[3], t); break;
        case 4: repack_body<15>(a.w[4], a.wpk[4], t); break;
        case 5: repack_body<23>(a.w[5], a.wpk[5], t); break;
        case 6: repack_body<37>(a.w[6], a.wpk[6], t); break;
        case 7: repack_body<55>(a.w[7], a.wpk[7], t); break;
    }
}

// ---- conv: 256 thr, 4 waves; wave = 64co x 128px x (1/4 of K16-chunks) ----
#define MFMA32 __builtin_amdgcn_mfma_f32_32x32x16_bf16

template<int K>
__device__ void conv_body(const float* __restrict__ x, const unsigned short* __restrict__ wpk,
                          const float* __restrict__ bias, unsigned short* __restrict__ feat,
                          int cbase, char* smem, int bx)
{
    constexpr int P        = KG<K>::P;
    constexpr int NCHKP16  = KG<K>::NCHKP16;
    constexpr int NSEC     = KG<K>::NSEC;
    constexpr int COLS     = KG<K>::COLS;
    constexpr int XSE      = KG<K>::XSE;

    unsigned short* xs0 = (unsigned short*)smem;   // two buffers of XSE elems
    float* red = (float*)smem;                     // aliases xs; used after xs dead

    const int tid = threadIdx.x;
    const int b   = bx >> 7;            // batch
    const int h   = bx & 127;           // image row

    const int lane = tid & 63;
    const int wv   = tid >> 6;          // 0..3 -> K-chunk quarter
    const int l31  = lane & 31;
    const int lh   = lane >> 5;         // k-half 0..1

    const float* xb = x + (size_t)b * 3 * HWPIX;

    // zero pad regions of BOTH buffers (tail-seg reads land there; stay zero)
    for (int i = tid * 4; i < KG<K>::XPAD; i += 1024) {
        *reinterpret_cast<short4v*>(xs0 + COLS * 24 + i)       = short4v{0, 0, 0, 0};
        *reinterpret_cast<short4v*>(xs0 + XSE + COLS * 24 + i) = short4v{0, 0, 0, 0};
    }

    auto stage = [&](int sec, unsigned short* dst) {
        for (int e = tid * 4; e < 24 * COLS; e += 1024) {
            const int c  = e / 24;
            const int i0 = e - c * 24;
            const int col = c - P;
            short4v pk;
            #pragma unroll
            for (int j = 0; j < 4; ++j) {
                const int icr = i0 + j;
                const int ic  = icr >> 3;
                const int row = h + sec * 8 + (icr & 7) - P;
                float v = 0.f;
                if ((unsigned)row < 128u && (unsigned)col < 128u)
                    v = xb[ic * HWPIX + row * 128 + col];
                pk[j] = (short)f2bf(v);
            }
            *reinterpret_cast<short4v*>(dst + e) = pk;
        }
    };

    stage(0, xs0);
    __syncthreads();

    f32x16 acc[2][4] = {};              // [co strip][px frag]

    for (int s = 0; s < NSEC; ++s) {
        if (s + 1 < NSEC) stage(s + 1, xs0 + ((s + 1) & 1) * XSE);

        const unsigned short* xsR  = xs0 + (s & 1) * XSE;
        const unsigned short* wsec = wpk + (size_t)s * NCHKP16 * 1024 + lane * 8;

        for (int tt = 0; tt < NCHKP16 / 4; ++tt) {
            const int t16 = tt * 4 + wv;
            const unsigned short* ap = wsec + (size_t)t16 * 1024;
            short8 a0 = *reinterpret_cast<const short8*>(ap);
            short8 a1 = *reinterpret_cast<const short8*>(ap + 512);
            const unsigned short* bp = xsR + l31 * 24 + lh * 8 + t16 * 16;
            short8 b0 = *reinterpret_cast<const short8*>(bp);
            short8 b1 = *reinterpret_cast<const short8*>(bp + 768);
            short8 b2 = *reinterpret_cast<const short8*>(bp + 1536);
            short8 b3 = *reinterpret_cast<const short8*>(bp + 2304);

            acc[0][0] = MFMA32(a0, b0, acc[0][0], 0, 0, 0);
            acc[0][1] = MFMA32(a0, b1, acc[0][1], 0, 0, 0);
            acc[0][2] = MFMA32(a0, b2, acc[0][2], 0, 0, 0);
            acc[0][3] = MFMA32(a0, b3, acc[0][3], 0, 0, 0);
            acc[1][0] = MFMA32(a1, b0, acc[1][0], 0, 0, 0);
            acc[1][1] = MFMA32(a1, b1, acc[1][1], 0, 0, 0);
            acc[1][2] = MFMA32(a1, b2, acc[1][2], 0, 0, 0);
            acc[1][3] = MFMA32(a1, b3, acc[1][3], 0, 0, 0);
        }
        __syncthreads();                 // next buffer staged & this one read
    }

    // ---- cross-wave reduction via LDS (xs dead after loop's last barrier) ----
    // D layout (32x32): px = q*32 + (lane&31); co_in_strip = (reg&3)+8*(reg>>2)+4*lh
    const float bv  = bias[tid >> 2];
    const int   eco = tid >> 2;          // 0..63
    const int   px8 = (tid & 3) * 8;     // 0,8,16,24
    const size_t fbase = (((size_t)(b * NCH + cbase + eco)) << 14) + h * 128;

    #pragma unroll
    for (int q = 0; q < 4; ++q) {
        if (q > 0) __syncthreads();      // previous pass's reads done
        #pragma unroll
        for (int strip = 0; strip < 2; ++strip)
            #pragma unroll
            for (int reg = 0; reg < 16; ++reg) {
                const int co = strip * 32 + (reg & 3) + 8 * (reg >> 2) + 4 * lh;
                red[(wv * 64 + co) * 33 + l31] = acc[strip][q][reg];
            }
        __syncthreads();
        short8 o;
        #pragma unroll
        for (int j = 0; j < 8; ++j) {
            const int px = px8 + j;
            float v = red[(0 * 64 + eco) * 33 + px] + red[(1 * 64 + eco) * 33 + px]
                    + red[(2 * 64 + eco) * 33 + px] + red[(3 * 64 + eco) * 33 + px];
            o[j] = (short)f2bf(fmaxf(v + bv, 0.f));
        }
        *reinterpret_cast<short8*>(feat + fbase + q * 32 + px8) = o;
    }
}

__global__ __launch_bounds__(256, 2) void conv_all(const float* __restrict__ x,
                                                   PtrArgs a, unsigned short* __restrict__ feat)
{
    __shared__ __align__(16) char smem[33792];   // max(2 x xs 17984B, red 256*33*4B)
    // LPT dispatch: heaviest filter (K=55) first so it spreads over all CUs
    switch (7 - blockIdx.y) {
        case 0: conv_body< 3>(x, a.wpk[0], a.bias[0], feat, 0 * 64, smem, blockIdx.x); break;
        case 1: conv_body< 5>(x, a.wpk[1], a.bias[1], feat, 1 * 64, smem, blockIdx.x); break;
        case 2: conv_body< 7>(x, a.wpk[2], a.bias[2], feat, 2 * 64, smem, blockIdx.x); break;
        case 3: conv_body<11>(x, a.wpk[3], a.bias[3], feat, 3 * 64, smem, blockIdx.x); break;
        case 4: conv_body<15>(x, a.wpk[4], a.bias[4], feat, 4 * 64, smem, blockIdx.x); break;
        case 5: conv_body<23>(x, a.wpk[5], a.bias[5], feat, 5 * 64, smem, blockIdx.x); break;
        case 6: conv_body<37>(x, a.wpk[6], a.bias[6], feat, 6 * 64, smem, blockIdx.x); break;
        case 7: conv_body<55>(x, a.wpk[7], a.bias[7], feat, 7 * 64, smem, blockIdx.x); break;
    }
}

// ---------------- gram via MFMA (unchanged, passing since r4) ----------------
#define MFMA_BF16 __builtin_amdgcn_mfma_f32_16x16x32_bf16

__global__ __launch_bounds__(256) void gram_mfma(
    const unsigned short* __restrict__ feat, const int* __restrict__ perm,
    float* __restrict__ part)
{
    __shared__ __align__(16) unsigned short tile[64 * 256];
    __shared__ int permch[64];

    const int bg = blockIdx.y, chunk = blockIdx.x;
    const int b = bg >> 3, gq = bg & 7;
    const int tid = threadIdx.x;

    if (tid < 64) permch[tid] = perm[gq * 64 + tid];
    __syncthreads();

    const int lane = tid & 63;
    const int wv   = tid >> 6;
    const int ln15 = lane & 15;
    const int kg   = lane >> 4;

    f32x4 acc[4] = {};
    const size_t pxbase = (size_t)chunk * 512;

    for (int p2 = 0; p2 < 2; ++p2) {
        {
            const int r0 = tid >> 5;        // 0..7
            const int g  = tid & 31;        // 16B group 0..31
            #pragma unroll
            for (int it = 0; it < 8; ++it) {
                const int r = it * 8 + r0;
                const unsigned short* src =
                    feat + (((size_t)(b * NCH + permch[r])) << 14) + pxbase + p2 * 256 + g * 8;
                short8 v = *reinterpret_cast<const short8*>(src);
                *reinterpret_cast<short8*>(tile + r * 256 + ((g ^ (r & 7)) * 8)) = v;
            }
        }
        __syncthreads();
        #pragma unroll
        for (int t = 0; t < 8; ++t) {
            const int g  = t * 4 + kg;
            const int ra = wv * 16 + ln15;
            short8 av = *reinterpret_cast<const short8*>(tile + ra * 256 + ((g ^ (ra & 7)) * 8));
            #pragma unroll
            for (int cs = 0; cs < 4; ++cs) {
                const int rb = cs * 16 + ln15;
                short8 bv = *reinterpret_cast<const short8*>(tile + rb * 256 + ((g ^ (rb & 7)) * 8));
                acc[cs] = MFMA_BF16(av, bv, acc[cs], 0, 0, 0);
            }
        }
        __syncthreads();
    }

    float* pp = part + ((size_t)bg * GCHK + chunk) * 4096;
    #pragma unroll
    for (int cs = 0; cs < 4; ++cs)
        #pragma unroll
        for (int i = 0; i < 4; ++i) {
            const int row = wv * 16 + kg * 4 + i;
            const int col = cs * 16 + ln15;
            pp[row * 64 + col] = acc[cs][i];
        }
}

__global__ __launch_bounds__(256) void gram_reduce(
    const float* __restrict__ part, float* __restrict__ out)
{
    const int idx = blockIdx.x * 256 + threadIdx.x;   // 0..65535
    const int bg  = idx >> 12;
    const int e   = idx & 4095;
    const float* p = part + (size_t)bg * GCHK * 4096 + e;
    float s = 0.f;
    #pragma unroll
    for (int c = 0; c < GCHK; ++c) s += p[c * 4096];
    out[idx] = s;
}

extern "C" void kernel_launch(void* const* d_in, const int* in_sizes, int n_in,
                              void* d_out, int out_size, void* d_ws, size_t ws_size,
                              hipStream_t stream) {
    const float* x = (const float*)d_in[0];
    const int* perm = (const int*)d_in[17];

    // ws: feat bf16 32MiB | part 8MiB | wpk 1092 chunks * 2KiB = 2.18MiB
    unsigned short* feat = (unsigned short*)d_ws;
    float* part = (float*)((char*)d_ws + (size_t)2 * NCH * HWPIX * sizeof(unsigned short));
    unsigned short* wpk0 = (unsigned short*)((char*)part + (size_t)16 * GCHK * 4096 * sizeof(float));
    float* out = (float*)d_out;

    const int nchk[8] = { KG<3>::NSEC * KG<3>::NCHKP16,  KG<5>::NSEC * KG<5>::NCHKP16,
                          KG<7>::NSEC * KG<7>::NCHKP16,  KG<11>::NSEC * KG<11>::NCHKP16,
                          KG<15>::NSEC * KG<15>::NCHKP16, KG<23>::NSEC * KG<23>::NCHKP16,
                          KG<37>::NSEC * KG<37>::NCHKP16, KG<55>::NSEC * KG<55>::NCHKP16 };
    PtrArgs a;
    int acc = 0;
    for (int i = 0; i < 8; ++i) {
        a.w[i]    = (const float*)d_in[1 + 2 * i];
        a.bias[i] = (const float*)d_in[2 + 2 * i];
        a.wpk[i]  = wpk0 + (size_t)acc * 1024;
        a.cum[i]  = acc;
        acc += nchk[i];
    }
    a.cum[8] = acc;   // 1092 total chunk-sections

    repack_all<<<acc, 256, 0, stream>>>(a);
    conv_all<<<dim3(256, 8), 256, 0, stream>>>(x, a, feat);
    gram_mfma<<<dim3(GCHK, 16), 256, 0, stream>>>(feat, perm, part);
    gram_reduce<<<dim3(65536 / 256), 256, 0, stream>>>(part, out);
}